// Round 22
// baseline (2090.720 us; speedup 1.0000x reference)
//
#include <hip/hip_runtime.h>
#include <float.h>

#define TT 4096
#define BB 4
#define CC 512
#define DD 256
#define KK 2048
#define MM (BB*TT)        // 16384 rows (b,t)
#define NBOOKS 22
#define EPS_PAIR 0.5f
#define EPS_FULL 0.5f
#define ZSTR 260          // 260 % 32 == 4 -> conflict-light (f32 panel)
#define ASTR 264          // f16 panel stride
#define RPB 32            // rows per block

typedef _Float16 half8_t __attribute__((ext_vector_type(8)));
typedef float f32x4 __attribute__((ext_vector_type(4)));

// ---- packed-u32 top-4 tracking ----
__device__ __forceinline__ uint32_t packsc(float s, int code) {
  uint32_t b = __float_as_uint(s);
  uint32_t key = b ^ ((uint32_t)((int32_t)b >> 31) | 0x80000000u);
  return (key & 0xFFFFF800u) | (uint32_t)code;
}
__device__ __forceinline__ float unpacksc(uint32_t p) {
  uint32_t key = p & 0xFFFFF800u;
  uint32_t b = (key & 0x80000000u) ? (key ^ 0x80000000u) : ~key;
  return __uint_as_float(b);
}
// branchless insert into sorted quad (7 min/max ops)
__device__ __forceinline__ void ins4(uint32_t& v1, uint32_t& v2, uint32_t& v3,
                                     uint32_t& v4, uint32_t p) {
  uint32_t t1 = max(v1, p);  v1 = min(v1, p);
  uint32_t t2 = max(v2, t1); v2 = min(v2, t1);
  uint32_t t3 = max(v3, t2); v3 = min(v3, t2);
  v4 = min(v4, t3);
}

// ---------------- projection: xs = Win_s @ x, xa = Win_a @ x ----------------
__global__ __launch_bounds__(256) void proj_kernel(const float* __restrict__ x,
    const float* __restrict__ Ws, const float* __restrict__ Wa,
    float* __restrict__ xs, float* __restrict__ xa)
{
  __shared__ float xt[16*64];
  __shared__ float wsl[16*68];
  __shared__ float wal[16*68];
  const int tid = threadIdx.x;
  const int t0 = blockIdx.x*64, d0 = blockIdx.y*64, b = blockIdx.z;
  const int u = tid & 63, cq = tid >> 6;
  const int tx = tid & 15, ty = tid >> 4;
  const float* xb = x + (size_t)b*CC*TT;
  float accS[4][4] = {{0}}, accA[4][4] = {{0}};
  for (int c0 = 0; c0 < CC; c0 += 16) {
    __syncthreads();
    #pragma unroll
    for (int i = 0; i < 4; ++i) {
      int cc = cq*4 + i;
      xt[cc*64 + u] = xb[(size_t)(c0+cc)*TT + t0 + u];
    }
    {
      float4 wv = *(const float4*)&Ws[(size_t)(d0+u)*CC + c0 + cq*4];
      wsl[(cq*4+0)*68 + u] = wv.x; wsl[(cq*4+1)*68 + u] = wv.y;
      wsl[(cq*4+2)*68 + u] = wv.z; wsl[(cq*4+3)*68 + u] = wv.w;
      wv = *(const float4*)&Wa[(size_t)(d0+u)*CC + c0 + cq*4];
      wal[(cq*4+0)*68 + u] = wv.x; wal[(cq*4+1)*68 + u] = wv.y;
      wal[(cq*4+2)*68 + u] = wv.z; wal[(cq*4+3)*68 + u] = wv.w;
    }
    __syncthreads();
    #pragma unroll
    for (int cc = 0; cc < 16; ++cc) {
      float4 tq = *(const float4*)&xt[cc*64 + ty*4];
      float4 sq = *(const float4*)&wsl[cc*68 + tx*4];
      float4 aq = *(const float4*)&wal[cc*68 + tx*4];
      float tf[4] = {tq.x,tq.y,tq.z,tq.w};
      float sf[4] = {sq.x,sq.y,sq.z,sq.w};
      float af[4] = {aq.x,aq.y,aq.z,aq.w};
      #pragma unroll
      for (int i = 0; i < 4; ++i)
        #pragma unroll
        for (int j = 0; j < 4; ++j) {
          accS[i][j] = fmaf(tf[i], sf[j], accS[i][j]);
          accA[i][j] = fmaf(tf[i], af[j], accA[i][j]);
        }
    }
  }
  #pragma unroll
  for (int i = 0; i < 4; ++i) {
    size_t r = (size_t)b*TT + t0 + ty*4 + i;
    float4 o;
    o.x = accS[i][0]; o.y = accS[i][1]; o.z = accS[i][2]; o.w = accS[i][3];
    *(float4*)&xs[r*DD + d0 + tx*4] = o;
    o.x = accA[i][0]; o.y = accA[i][1]; o.z = accA[i][2]; o.w = accA[i][3];
    *(float4*)&xa[r*DD + d0 + tx*4] = o;
  }
}

// ---------------- e2[k] = sum_d E[k][d]^2 ----------------
__global__ __launch_bounds__(256) void e2_kernel(const float* __restrict__ E,
    float* __restrict__ e2)
{
  int gid = blockIdx.x*256 + threadIdx.x;
  int wid = gid >> 6, lane = gid & 63;
  if (wid < 18*KK) {
    float4 v = *(const float4*)&E[(size_t)wid*DD + lane*4];
    float s = v.x*v.x + v.y*v.y + v.z*v.z + v.w*v.w;
    #pragma unroll
    for (int m = 1; m <= 32; m <<= 1) s += __shfl_xor(s, m);
    if (lane == 0) e2[wid] = s;
  }
}

// ---------------- convert E -> f16 plane ----------------
__global__ __launch_bounds__(256) void cvt_e16_kernel(const float* __restrict__ E,
    _Float16* __restrict__ E16)
{
  size_t i = ((size_t)blockIdx.x*256 + threadIdx.x)*8;
  float4 u = *(const float4*)&E[i];
  float4 v = *(const float4*)&E[i+4];
  half8_t h;
  h[0]=(_Float16)u.x; h[1]=(_Float16)u.y; h[2]=(_Float16)u.z; h[3]=(_Float16)u.w;
  h[4]=(_Float16)v.x; h[5]=(_Float16)v.y; h[6]=(_Float16)v.z; h[7]=(_Float16)v.w;
  *(half8_t*)&E16[i] = h;
}

// ---------------- FUSED encode: all 22 books, one kernel ----------------
// 512 blocks x 32 rows, 512 threads = 8 WAVES (wave owns a 256-code
// eighth). A in LDS keeps per-lane demand ~95 VGPR <= the 128 cap for
// 8-wave blocks (r16's spill cause removed). LDS ~55KB -> 2 blocks/CU
// -> 16 waves/CU = 4 waves/SIMD: double the TLP of every prior round at
// identical per-block book traffic. Top-4 tracking + exact-fp64
// candidate refine (r21); full re-rank only on rare 4-way ties.
__global__ __launch_bounds__(512)
void fused_encode_kernel(
    const float* __restrict__ xs_g, const float* __restrict__ xa_g,
    const float* __restrict__ E, const _Float16* __restrict__ E16,
    const float* __restrict__ e2, int* __restrict__ codes0,
    float* __restrict__ codes_f, float* __restrict__ aco_g)
{
  const int tid = threadIdx.x;
  const int lane = tid & 63, wave = tid >> 6;   // 8 waves
  const int ln15 = lane & 15, lq = lane >> 4;   // lq 0..3
  const int row0 = blockIdx.x * RPB;

  __shared__ float Z[RPB][ZSTR];                // residual panel f32 (~33.3KB)
  __shared__ _Float16 A16[RPB][ASTR];           // f16 fragment panel (~16.9KB)
  __shared__ uint32_t L1[8][RPB], L2[8][RPB], L3[8][RPB], L4[8][RPB];
  __shared__ int   codes_s[RPB];
  __shared__ int   flist[RPB];
  __shared__ int   cA[RPB], cB[RPB];
  __shared__ int   nfull, ncand;
  __shared__ double Rv[8];
  __shared__ int    Ri[8];

  const int ldr = tid >> 4, cg = tid & 15;      // staging: 16 thr/row, 16 f each

  for (int ib = 0; ib < NBOOKS; ++ib) {
    const int book = (ib <= 17) ? ib : 17;
    const float*     Eb   = E   + (size_t)book*KK*DD;
    const _Float16*  E16b = E16 + (size_t)book*KK*DD;
    const float*     e2b  = e2  + (size_t)book*KK;

    if (ib <= 1) {                              // ib0: xs panel; ib1: xa panel
      const float* src = (ib == 0) ? xs_g : xa_g;
      const float* sp = src + (size_t)(row0 + ldr)*DD;
      #pragma unroll
      for (int j = 0; j < 4; ++j)
        *(float4*)&Z[ldr][cg*4 + j*64] = *(const float4*)(sp + cg*4 + j*64);
    }
    if (tid == 0) { nfull = 0; ncand = 0; }
    __syncthreads();                            // S1: Z current

    // ---- convert Z -> A16 (f32 -> f16 panel in LDS): 16 floats/thread ----
    {
      int vc = cg*16;
      #pragma unroll
      for (int j = 0; j < 2; ++j) {
        float4 u = *(const float4*)&Z[ldr][vc + j*8];
        float4 v = *(const float4*)&Z[ldr][vc + j*8 + 4];
        half8_t h;
        h[0]=(_Float16)u.x; h[1]=(_Float16)u.y; h[2]=(_Float16)u.z; h[3]=(_Float16)u.w;
        h[4]=(_Float16)v.x; h[5]=(_Float16)v.y; h[6]=(_Float16)v.z; h[7]=(_Float16)v.w;
        *(half8_t*)&A16[ldr][vc + j*8] = h;
      }
    }
    __syncthreads();                            // S1b: A16 ready

    uint32_t p1[2][4], p2[2][4], p3[2][4], p4[2][4];
    #pragma unroll
    for (int mt = 0; mt < 2; ++mt)
      #pragma unroll
      for (int j = 0; j < 4; ++j) {
        p1[mt][j] = 0xFFFFFFFFu; p2[mt][j] = 0xFFFFFFFFu;
        p3[mt][j] = 0xFFFFFFFFu; p4[mt][j] = 0xFFFFFFFFu;
      }

    const _Float16* ebase = E16b + (size_t)(wave*256 + ln15)*DD + lq*8;
    const _Float16* a0p = &A16[ln15][lq*8];
    const _Float16* a1p = &A16[16 + ln15][lq*8];

    // ---- search: nt-pair per iteration, 4 MFMA chains, A read once/ks ----
    for (int nt = 0; nt < 16; nt += 2) {
      const _Float16* bp0 = ebase + (size_t)nt*16*DD;
      const _Float16* bp1 = bp0 + 16*DD;
      half8_t B0[8];
      #pragma unroll
      for (int ks = 0; ks < 8; ++ks) B0[ks] = *(const half8_t*)(bp0 + ks*32);
      f32x4 a00 = (f32x4){0.f,0.f,0.f,0.f};
      f32x4 a01 = (f32x4){0.f,0.f,0.f,0.f};
      f32x4 a10 = (f32x4){0.f,0.f,0.f,0.f};
      f32x4 a11 = (f32x4){0.f,0.f,0.f,0.f};
      #pragma unroll
      for (int ks = 0; ks < 8; ++ks) {
        half8_t B1k = *(const half8_t*)(bp1 + ks*32);
        half8_t fa0 = *(const half8_t*)(a0p + ks*32);
        half8_t fa1 = *(const half8_t*)(a1p + ks*32);
        a00 = __builtin_amdgcn_mfma_f32_16x16x32_f16(fa0, B0[ks], a00, 0, 0, 0);
        a01 = __builtin_amdgcn_mfma_f32_16x16x32_f16(fa1, B0[ks], a01, 0, 0, 0);
        a10 = __builtin_amdgcn_mfma_f32_16x16x32_f16(fa0, B1k, a10, 0, 0, 0);
        a11 = __builtin_amdgcn_mfma_f32_16x16x32_f16(fa1, B1k, a11, 0, 0, 0);
      }
      int code0 = wave*256 + nt*16 + ln15;
      int code1 = code0 + 16;
      float e20 = e2b[code0], e21 = e2b[code1];
      // C/D: col(code)=lane&15, row=(lane>>4)*4+reg
      #pragma unroll
      for (int j = 0; j < 4; ++j) {
        ins4(p1[0][j], p2[0][j], p3[0][j], p4[0][j], packsc(fmaf(-2.f, a00[j], e20), code0));
        ins4(p1[1][j], p2[1][j], p3[1][j], p4[1][j], packsc(fmaf(-2.f, a01[j], e20), code0));
        ins4(p1[0][j], p2[0][j], p3[0][j], p4[0][j], packsc(fmaf(-2.f, a10[j], e21), code1));
        ins4(p1[1][j], p2[1][j], p3[1][j], p4[1][j], packsc(fmaf(-2.f, a11[j], e21), code1));
      }
    }

    // ---- in-wave reduce over the 16 code-columns, then cross-wave ----
    #pragma unroll
    for (int mt = 0; mt < 2; ++mt)
      #pragma unroll
      for (int j = 0; j < 4; ++j) {
        uint32_t v1 = p1[mt][j], v2 = p2[mt][j], v3 = p3[mt][j], v4 = p4[mt][j];
        #pragma unroll
        for (int m = 1; m <= 8; m <<= 1) {
          uint32_t w1 = (uint32_t)__shfl_xor((int)v1, m);
          uint32_t w2 = (uint32_t)__shfl_xor((int)v2, m);
          uint32_t w3 = (uint32_t)__shfl_xor((int)v3, m);
          uint32_t w4 = (uint32_t)__shfl_xor((int)v4, m);
          ins4(v1, v2, v3, v4, w1);
          ins4(v1, v2, v3, v4, w2);
          ins4(v1, v2, v3, v4, w3);
          ins4(v1, v2, v3, v4, w4);
        }
        if (ln15 == 0) {
          int rl = mt*16 + lq*4 + j;
          L1[wave][rl] = v1; L2[wave][rl] = v2;
          L3[wave][rl] = v3; L4[wave][rl] = v4;
        }
      }
    __syncthreads();                            // S2
    if (tid < RPB) {
      uint32_t v1 = L1[0][tid], v2 = L2[0][tid], v3 = L3[0][tid], v4 = L4[0][tid];
      #pragma unroll
      for (int w = 1; w < 8; ++w) {
        ins4(v1, v2, v3, v4, L1[w][tid]);
        ins4(v1, v2, v3, v4, L2[w][tid]);
        ins4(v1, v2, v3, v4, L3[w][tid]);
        ins4(v1, v2, v3, v4, L4[w][tid]);
      }
      int a1 = (int)(v1 & 2047u), a2 = (int)(v2 & 2047u), a3 = (int)(v3 & 2047u);
      float f1 = unpacksc(v1), f2 = unpacksc(v2), f4 = unpacksc(v4);
      codes_s[tid] = a1;
      int rg = row0 + tid;
      codes_f[((size_t)(rg >> 12)*NBOOKS + ib)*TT + (rg & (TT-1))] = (float)a1;
      if (ib == 0) codes0[rg] = a1;
      if (f4 - f1 < EPS_FULL) {
        flist[atomicAdd(&nfull, 1)] = tid;
      } else if (f2 - f1 < EPS_PAIR) {
        int p = atomicAdd(&ncand, 1);
        cA[p] = tid | (a1 << 6) | (a2 << 17);
        cB[p] = a3;
      }
    }
    __syncthreads();                            // S3

    // ---- full fp64 re-rank (RARE: 4 codes within EPS of best) ----
    int nfl = nfull;
    for (int f = 0; f < nfl; ++f) {
      int row = flist[f];
      double bestv = DBL_MAX; int besti = 0x7fffffff;
      #pragma unroll
      for (int q = 0; q < 4; ++q) {
        int k = q*512 + tid;
        const float* er = Eb + (size_t)k*DD;
        double s0 = 0.0, s1 = 0.0;
        for (int d = 0; d < DD; d += 8) {
          float4 e0 = *(const float4*)(er + d);
          float4 e1 = *(const float4*)(er + d + 4);
          double x0 = (double)Z[row][d+0] - (double)e0.x;
          double x1 = (double)Z[row][d+1] - (double)e0.y;
          double x2 = (double)Z[row][d+2] - (double)e0.z;
          double x3 = (double)Z[row][d+3] - (double)e0.w;
          s0 += x0*x0 + x1*x1 + x2*x2 + x3*x3;
          double x4 = (double)Z[row][d+4] - (double)e1.x;
          double x5 = (double)Z[row][d+5] - (double)e1.y;
          double x6 = (double)Z[row][d+6] - (double)e1.z;
          double x7 = (double)Z[row][d+7] - (double)e1.w;
          s1 += x4*x4 + x5*x5 + x6*x6 + x7*x7;
        }
        double s = s0 + s1;
        if (s < bestv || (s == bestv && k < besti)) { bestv = s; besti = k; }
      }
      #pragma unroll
      for (int m = 1; m <= 32; m <<= 1) {
        double ov = __shfl_xor(bestv, m);
        int    oi = __shfl_xor(besti, m);
        if (ov < bestv || (ov == bestv && oi < besti)) { bestv = ov; besti = oi; }
      }
      if (lane == 0) { Rv[wave] = bestv; Ri[wave] = besti; }
      __syncthreads();
      if (tid == 0) {
        double bvv = Rv[0]; int bii = Ri[0];
        #pragma unroll
        for (int w = 1; w < 8; ++w)
          if (Rv[w] < bvv || (Rv[w] == bvv && Ri[w] < bii)) { bvv = Rv[w]; bii = Ri[w]; }
        codes_s[row] = bii;
        int rg = row0 + row;
        codes_f[((size_t)(rg >> 12)*NBOOKS + ib)*TT + (rg & (TT-1))] = (float)bii;
        if (ib == 0) codes0[rg] = bii;
      }
      __syncthreads();
    }

    // ---- candidate refine: exact fp64 over top-3 (one wave per row) ----
    {
      int ncd = ncand;
      for (int f = wave; f < ncd; f += 8) {
        int pk = cA[f];
        int row = pk & 63;
        int cand[3];
        cand[0] = (pk >> 6) & 2047;
        cand[1] = (pk >> 17) & 2047;
        cand[2] = cB[f];
        double bv = DBL_MAX; int bi = 0x7fffffff;
        #pragma unroll
        for (int t = 0; t < 3; ++t) {
          int cc = cand[t];
          const float* er = Eb + (size_t)cc*DD + lane*4;
          const float* zr = &Z[row][lane*4];
          double d0 = (double)zr[0] - (double)er[0];
          double d1 = (double)zr[1] - (double)er[1];
          double d2 = (double)zr[2] - (double)er[2];
          double d3 = (double)zr[3] - (double)er[3];
          double s = d0*d0 + d1*d1 + d2*d2 + d3*d3;
          #pragma unroll
          for (int m = 1; m <= 32; m <<= 1) s += __shfl_xor(s, m);
          if (s < bv || (s == bv && cc < bi)) { bv = s; bi = cc; }
        }
        if (lane == 0) {
          codes_s[row] = bi;
          int rg = row0 + row;
          codes_f[((size_t)(rg >> 12)*NBOOKS + ib)*TT + (rg & (TT-1))] = (float)bi;
          if (ib == 0) codes0[rg] = bi;
        }
      }
    }
    __syncthreads();                            // S4: codes_s final

    // ---- f32 residual subtract in LDS (acoustic books only) ----
    if (ib >= 1) {
      int code = codes_s[ldr];
      const float* er = Eb + (size_t)code*DD;
      #pragma unroll
      for (int j = 0; j < 4; ++j) {
        int c = cg*4 + j*64;
        float4 e = *(const float4*)(er + c);
        float4 z = *(const float4*)&Z[ldr][c];
        z.x -= e.x; z.y -= e.y; z.z -= e.z; z.w -= e.w;
        *(float4*)&Z[ldr][c] = z;
      }
    }
    __syncthreads();                            // S5: Z stable for next book
  }

  // ---- aco = xa_initial - xa_final ----
  {
    const float* xp = xa_g + (size_t)(row0 + ldr)*DD;
    float*       ap = aco_g + (size_t)(row0 + ldr)*DD;
    #pragma unroll
    for (int j = 0; j < 4; ++j) {
      int c = cg*4 + j*64;
      float4 x0 = *(const float4*)(xp + c);
      float4 zf = *(const float4*)&Z[ldr][c];
      float4 o;
      o.x = x0.x - zf.x; o.y = x0.y - zf.y; o.z = x0.z - zf.z; o.w = x0.w - zf.w;
      *(float4*)(ap + c) = o;
    }
  }
}

// ---------------- decode ----------------
__global__ __launch_bounds__(256) void final_kernel(
    const float* __restrict__ Wos, const float* __restrict__ Woa,
    const float* __restrict__ E0, const int* __restrict__ codes0,
    const float* __restrict__ aco, float* __restrict__ out)
{
  __shared__ float wsl[16*68], wal[16*68], sml[16*68], acl[16*68];
  const int tid = threadIdx.x;
  const int t0 = blockIdx.x*64, c0 = blockIdx.y*64, b = blockIdx.z;
  const int u = tid & 63, dq = tid >> 6;
  const int tx = tid & 15, ty = tid >> 4;
  int code = codes0[b*TT + t0 + u];
  const float* smr = E0 + (size_t)code*DD;
  const float* acr = aco + (size_t)(b*TT + t0 + u)*DD;
  const float* wsr = Wos + (size_t)(c0+u)*DD;
  const float* war = Woa + (size_t)(c0+u)*DD;
  float accS[4][4] = {{0}}, accA[4][4] = {{0}};
  for (int dc0 = 0; dc0 < DD; dc0 += 16) {
    __syncthreads();
    float4 v;
    v = *(const float4*)(wsr + dc0 + dq*4);
    wsl[(dq*4+0)*68+u]=v.x; wsl[(dq*4+1)*68+u]=v.y; wsl[(dq*4+2)*68+u]=v.z; wsl[(dq*4+3)*68+u]=v.w;
    v = *(const float4*)(war + dc0 + dq*4);
    wal[(dq*4+0)*68+u]=v.x; wal[(dq*4+1)*68+u]=v.y; wal[(dq*4+2)*68+u]=v.z; wal[(dq*4+3)*68+u]=v.w;
    v = *(const float4*)(smr + dc0 + dq*4);
    sml[(dq*4+0)*68+u]=v.x; sml[(dq*4+1)*68+u]=v.y; sml[(dq*4+2)*68+u]=v.z; sml[(dq*4+3)*68+u]=v.w;
    v = *(const float4*)(acr + dc0 + dq*4);
    acl[(dq*4+0)*68+u]=v.x; acl[(dq*4+1)*68+u]=v.y; acl[(dq*4+2)*68+u]=v.z; acl[(dq*4+3)*68+u]=v.w;
    __syncthreads();
    #pragma unroll
    for (int d = 0; d < 16; ++d) {
      float4 cs = *(const float4*)&wsl[d*68 + tx*4];
      float4 ca = *(const float4*)&wal[d*68 + tx*4];
      float4 ts = *(const float4*)&sml[d*68 + ty*4];
      float4 ta = *(const float4*)&acl[d*68 + ty*4];
      float csf[4]={cs.x,cs.y,cs.z,cs.w}, caf[4]={ca.x,ca.y,ca.z,ca.w};
      float tsf[4]={ts.x,ts.y,ts.z,ts.w}, taf[4]={ta.x,ta.y,ta.z,ta.w};
      #pragma unroll
      for (int i = 0; i < 4; ++i)
        #pragma unroll
        for (int j = 0; j < 4; ++j) {
          accS[i][j] = fmaf(csf[i], tsf[j], accS[i][j]);
          accA[i][j] = fmaf(caf[i], taf[j], accA[i][j]);
        }
    }
  }
  size_t ob = (size_t)b*CC*TT;
  #pragma unroll
  for (int i = 0; i < 4; ++i) {
    float4 r;
    r.x = accS[i][0] + accA[i][0];
    r.y = accS[i][1] + accA[i][1];
    r.z = accS[i][2] + accA[i][2];
    r.w = accS[i][3] + accA[i][3];
    *(float4*)&out[ob + (size_t)(c0 + tx*4 + i)*TT + t0 + ty*4] = r;
  }
}

extern "C" void kernel_launch(void* const* d_in, const int* in_sizes, int n_in,
                              void* d_out, int out_size, void* d_ws, size_t ws_size,
                              hipStream_t stream) {
  const float* x    = (const float*)d_in[0];
  const float* Wins = (const float*)d_in[1];
  const float* Wina = (const float*)d_in[2];
  const float* Wos  = (const float*)d_in[3];
  const float* Woa  = (const float*)d_in[4];
  const float* E    = (const float*)d_in[5];
  float* out = (float*)d_out;
  float* codes_f = out + (size_t)BB*CC*TT;

  // E16 plane lives in the front of d_out (18.9MB; codes_f starts at 33.6MB;
  // out[0:8.4M floats] fully overwritten by final_kernel afterwards).
  _Float16* E16 = (_Float16*)d_out;

  float* xs  = (float*)d_ws;
  float* xa  = xs + (size_t)MM*DD;
  float* aco = xa + (size_t)MM*DD;
  float* e2  = aco + (size_t)MM*DD;
  int* codes_i = (int*)(e2 + 18*KK);

  proj_kernel<<<dim3(TT/64, DD/64, BB), 256, 0, stream>>>(x, Wins, Wina, xs, xa);
  e2_kernel<<<(18*KK*64)/256, 256, 0, stream>>>(E, e2);
  cvt_e16_kernel<<<(18*KK*DD)/8/256, 256, 0, stream>>>(E, E16);

  fused_encode_kernel<<<MM/RPB, 512, 0, stream>>>(xs, xa, E, E16, e2,
                                                  codes_i, codes_f, aco);

  final_kernel<<<dim3(TT/64, CC/64, BB), 256, 0, stream>>>(Wos, Woa, E, codes_i, aco, out);
}

// Round 23
// 1672.215 us; speedup vs baseline: 1.2503x; 1.2503x over previous
//
#include <hip/hip_runtime.h>
#include <float.h>

#define TT 4096
#define BB 4
#define CC 512
#define DD 256
#define KK 2048
#define MM (BB*TT)        // 16384 rows (b,t)
#define NBOOKS 22
#define EPS_PAIR 0.5f
#define EPS_FULL 0.5f
#define ZSTR 260          // 260 % 32 == 4 -> conflict-light (f32 panel)
#define ASTR 264          // f16 panel stride
#define RPB 32            // rows per block

typedef _Float16 half8_t __attribute__((ext_vector_type(8)));
typedef float f32x4 __attribute__((ext_vector_type(4)));

// ---- packed-u32 top-4 tracking ----
__device__ __forceinline__ uint32_t packsc(float s, int code) {
  uint32_t b = __float_as_uint(s);
  uint32_t key = b ^ ((uint32_t)((int32_t)b >> 31) | 0x80000000u);
  return (key & 0xFFFFF800u) | (uint32_t)code;
}
__device__ __forceinline__ float unpacksc(uint32_t p) {
  uint32_t key = p & 0xFFFFF800u;
  uint32_t b = (key & 0x80000000u) ? (key ^ 0x80000000u) : ~key;
  return __uint_as_float(b);
}
// branchless insert into sorted quad (7 min/max ops)
__device__ __forceinline__ void ins4(uint32_t& v1, uint32_t& v2, uint32_t& v3,
                                     uint32_t& v4, uint32_t p) {
  uint32_t t1 = max(v1, p);  v1 = min(v1, p);
  uint32_t t2 = max(v2, t1); v2 = min(v2, t1);
  uint32_t t3 = max(v3, t2); v3 = min(v3, t2);
  v4 = min(v4, t3);
}

// ---------------- projection: xs = Win_s @ x, xa = Win_a @ x ----------------
__global__ __launch_bounds__(256) void proj_kernel(const float* __restrict__ x,
    const float* __restrict__ Ws, const float* __restrict__ Wa,
    float* __restrict__ xs, float* __restrict__ xa)
{
  __shared__ float xt[16*64];
  __shared__ float wsl[16*68];
  __shared__ float wal[16*68];
  const int tid = threadIdx.x;
  const int t0 = blockIdx.x*64, d0 = blockIdx.y*64, b = blockIdx.z;
  const int u = tid & 63, cq = tid >> 6;
  const int tx = tid & 15, ty = tid >> 4;
  const float* xb = x + (size_t)b*CC*TT;
  float accS[4][4] = {{0}}, accA[4][4] = {{0}};
  for (int c0 = 0; c0 < CC; c0 += 16) {
    __syncthreads();
    #pragma unroll
    for (int i = 0; i < 4; ++i) {
      int cc = cq*4 + i;
      xt[cc*64 + u] = xb[(size_t)(c0+cc)*TT + t0 + u];
    }
    {
      float4 wv = *(const float4*)&Ws[(size_t)(d0+u)*CC + c0 + cq*4];
      wsl[(cq*4+0)*68 + u] = wv.x; wsl[(cq*4+1)*68 + u] = wv.y;
      wsl[(cq*4+2)*68 + u] = wv.z; wsl[(cq*4+3)*68 + u] = wv.w;
      wv = *(const float4*)&Wa[(size_t)(d0+u)*CC + c0 + cq*4];
      wal[(cq*4+0)*68 + u] = wv.x; wal[(cq*4+1)*68 + u] = wv.y;
      wal[(cq*4+2)*68 + u] = wv.z; wal[(cq*4+3)*68 + u] = wv.w;
    }
    __syncthreads();
    #pragma unroll
    for (int cc = 0; cc < 16; ++cc) {
      float4 tq = *(const float4*)&xt[cc*64 + ty*4];
      float4 sq = *(const float4*)&wsl[cc*68 + tx*4];
      float4 aq = *(const float4*)&wal[cc*68 + tx*4];
      float tf[4] = {tq.x,tq.y,tq.z,tq.w};
      float sf[4] = {sq.x,sq.y,sq.z,sq.w};
      float af[4] = {aq.x,aq.y,aq.z,aq.w};
      #pragma unroll
      for (int i = 0; i < 4; ++i)
        #pragma unroll
        for (int j = 0; j < 4; ++j) {
          accS[i][j] = fmaf(tf[i], sf[j], accS[i][j]);
          accA[i][j] = fmaf(tf[i], af[j], accA[i][j]);
        }
    }
  }
  #pragma unroll
  for (int i = 0; i < 4; ++i) {
    size_t r = (size_t)b*TT + t0 + ty*4 + i;
    float4 o;
    o.x = accS[i][0]; o.y = accS[i][1]; o.z = accS[i][2]; o.w = accS[i][3];
    *(float4*)&xs[r*DD + d0 + tx*4] = o;
    o.x = accA[i][0]; o.y = accA[i][1]; o.z = accA[i][2]; o.w = accA[i][3];
    *(float4*)&xa[r*DD + d0 + tx*4] = o;
  }
}

// ---------------- e2[k] = sum_d E[k][d]^2 ----------------
__global__ __launch_bounds__(256) void e2_kernel(const float* __restrict__ E,
    float* __restrict__ e2)
{
  int gid = blockIdx.x*256 + threadIdx.x;
  int wid = gid >> 6, lane = gid & 63;
  if (wid < 18*KK) {
    float4 v = *(const float4*)&E[(size_t)wid*DD + lane*4];
    float s = v.x*v.x + v.y*v.y + v.z*v.z + v.w*v.w;
    #pragma unroll
    for (int m = 1; m <= 32; m <<= 1) s += __shfl_xor(s, m);
    if (lane == 0) e2[wid] = s;
  }
}

// ---------------- convert E -> f16 plane ----------------
__global__ __launch_bounds__(256) void cvt_e16_kernel(const float* __restrict__ E,
    _Float16* __restrict__ E16)
{
  size_t i = ((size_t)blockIdx.x*256 + threadIdx.x)*8;
  float4 u = *(const float4*)&E[i];
  float4 v = *(const float4*)&E[i+4];
  half8_t h;
  h[0]=(_Float16)u.x; h[1]=(_Float16)u.y; h[2]=(_Float16)u.z; h[3]=(_Float16)u.w;
  h[4]=(_Float16)v.x; h[5]=(_Float16)v.y; h[6]=(_Float16)v.z; h[7]=(_Float16)v.w;
  *(half8_t*)&E16[i] = h;
}

// ---------------- FUSED encode: all 22 books, one kernel ----------------
// Proven-best r21 config: 512 blocks x 32 rows, 256 threads = 4 waves.
// A in LDS; nt-pair / 4-chain search; TOP-4 tracking: if 4th-best is
// >= EPS from best, true argmin provably in top-3 -> refine = 3 exact
// fp64 distances. Full fp64 re-rank only on rare 4-way ties.
__global__ __launch_bounds__(256)
void fused_encode_kernel(
    const float* __restrict__ xs_g, const float* __restrict__ xa_g,
    const float* __restrict__ E, const _Float16* __restrict__ E16,
    const float* __restrict__ e2, int* __restrict__ codes0,
    float* __restrict__ codes_f, float* __restrict__ aco_g)
{
  const int tid = threadIdx.x;
  const int lane = tid & 63, wave = tid >> 6;   // 4 waves
  const int ln15 = lane & 15, lq = lane >> 4;   // lq 0..3
  const int row0 = blockIdx.x * RPB;

  __shared__ float Z[RPB][ZSTR];                // residual panel f32 (~33.3KB)
  __shared__ _Float16 A16[RPB][ASTR];           // f16 fragment panel (~16.9KB)
  __shared__ uint32_t L1[4][RPB], L2[4][RPB], L3[4][RPB], L4[4][RPB];
  __shared__ int   codes_s[RPB];
  __shared__ int   flist[RPB];
  __shared__ int   cA[RPB], cB[RPB];
  __shared__ int   nfull, ncand;
  __shared__ double Rv[4];
  __shared__ int    Ri[4];

  const int ldr = tid & 31, cg = tid >> 5;      // panel-load / aco mapping
  const int sr = tid >> 3, sg = tid & 7;        // subtract mapping (8 thr/row)
  const int vr = tid >> 3, vc = (tid & 7)*32;   // convert mapping (32 f per thr)

  for (int ib = 0; ib < NBOOKS; ++ib) {
    const int book = (ib <= 17) ? ib : 17;
    const float*     Eb   = E   + (size_t)book*KK*DD;
    const _Float16*  E16b = E16 + (size_t)book*KK*DD;
    const float*     e2b  = e2  + (size_t)book*KK;

    if (ib <= 1) {                              // ib0: xs panel; ib1: xa panel
      const float* src = (ib == 0) ? xs_g : xa_g;
      const float* sp = src + (size_t)(row0 + ldr)*DD + cg*32;
      #pragma unroll
      for (int j = 0; j < 8; ++j)
        *(float4*)&Z[ldr][cg*32 + j*4] = *(const float4*)(sp + j*4);
    }
    if (tid == 0) { nfull = 0; ncand = 0; }
    __syncthreads();                            // S1: Z current

    // ---- convert Z -> A16 (f32 -> f16 panel in LDS) ----
    #pragma unroll
    for (int j = 0; j < 4; ++j) {
      float4 u = *(const float4*)&Z[vr][vc + j*8];
      float4 v = *(const float4*)&Z[vr][vc + j*8 + 4];
      half8_t h;
      h[0]=(_Float16)u.x; h[1]=(_Float16)u.y; h[2]=(_Float16)u.z; h[3]=(_Float16)u.w;
      h[4]=(_Float16)v.x; h[5]=(_Float16)v.y; h[6]=(_Float16)v.z; h[7]=(_Float16)v.w;
      *(half8_t*)&A16[vr][vc + j*8] = h;
    }
    __syncthreads();                            // S1b: A16 ready

    uint32_t p1[2][4], p2[2][4], p3[2][4], p4[2][4];
    #pragma unroll
    for (int mt = 0; mt < 2; ++mt)
      #pragma unroll
      for (int j = 0; j < 4; ++j) {
        p1[mt][j] = 0xFFFFFFFFu; p2[mt][j] = 0xFFFFFFFFu;
        p3[mt][j] = 0xFFFFFFFFu; p4[mt][j] = 0xFFFFFFFFu;
      }

    const _Float16* ebase = E16b + (size_t)(wave*512 + ln15)*DD + lq*8;
    const _Float16* a0p = &A16[ln15][lq*8];
    const _Float16* a1p = &A16[16 + ln15][lq*8];

    // ---- search: nt-pair per iteration, 4 MFMA chains, A read once/ks ----
    for (int nt = 0; nt < 32; nt += 2) {
      const _Float16* bp0 = ebase + (size_t)nt*16*DD;
      const _Float16* bp1 = bp0 + 16*DD;
      half8_t B0[8];
      #pragma unroll
      for (int ks = 0; ks < 8; ++ks) B0[ks] = *(const half8_t*)(bp0 + ks*32);
      f32x4 a00 = (f32x4){0.f,0.f,0.f,0.f};
      f32x4 a01 = (f32x4){0.f,0.f,0.f,0.f};
      f32x4 a10 = (f32x4){0.f,0.f,0.f,0.f};
      f32x4 a11 = (f32x4){0.f,0.f,0.f,0.f};
      #pragma unroll
      for (int ks = 0; ks < 8; ++ks) {
        half8_t B1k = *(const half8_t*)(bp1 + ks*32);
        half8_t fa0 = *(const half8_t*)(a0p + ks*32);
        half8_t fa1 = *(const half8_t*)(a1p + ks*32);
        a00 = __builtin_amdgcn_mfma_f32_16x16x32_f16(fa0, B0[ks], a00, 0, 0, 0);
        a01 = __builtin_amdgcn_mfma_f32_16x16x32_f16(fa1, B0[ks], a01, 0, 0, 0);
        a10 = __builtin_amdgcn_mfma_f32_16x16x32_f16(fa0, B1k, a10, 0, 0, 0);
        a11 = __builtin_amdgcn_mfma_f32_16x16x32_f16(fa1, B1k, a11, 0, 0, 0);
      }
      int code0 = wave*512 + nt*16 + ln15;
      int code1 = code0 + 16;
      float e20 = e2b[code0], e21 = e2b[code1];
      // C/D: col(code)=lane&15, row=(lane>>4)*4+reg
      #pragma unroll
      for (int j = 0; j < 4; ++j) {
        ins4(p1[0][j], p2[0][j], p3[0][j], p4[0][j], packsc(fmaf(-2.f, a00[j], e20), code0));
        ins4(p1[1][j], p2[1][j], p3[1][j], p4[1][j], packsc(fmaf(-2.f, a01[j], e20), code0));
        ins4(p1[0][j], p2[0][j], p3[0][j], p4[0][j], packsc(fmaf(-2.f, a10[j], e21), code1));
        ins4(p1[1][j], p2[1][j], p3[1][j], p4[1][j], packsc(fmaf(-2.f, a11[j], e21), code1));
      }
    }

    // ---- in-wave reduce over the 16 code-columns, then cross-wave ----
    #pragma unroll
    for (int mt = 0; mt < 2; ++mt)
      #pragma unroll
      for (int j = 0; j < 4; ++j) {
        uint32_t v1 = p1[mt][j], v2 = p2[mt][j], v3 = p3[mt][j], v4 = p4[mt][j];
        #pragma unroll
        for (int m = 1; m <= 8; m <<= 1) {
          uint32_t w1 = (uint32_t)__shfl_xor((int)v1, m);
          uint32_t w2 = (uint32_t)__shfl_xor((int)v2, m);
          uint32_t w3 = (uint32_t)__shfl_xor((int)v3, m);
          uint32_t w4 = (uint32_t)__shfl_xor((int)v4, m);
          ins4(v1, v2, v3, v4, w1);
          ins4(v1, v2, v3, v4, w2);
          ins4(v1, v2, v3, v4, w3);
          ins4(v1, v2, v3, v4, w4);
        }
        if (ln15 == 0) {
          int rl = mt*16 + lq*4 + j;
          L1[wave][rl] = v1; L2[wave][rl] = v2;
          L3[wave][rl] = v3; L4[wave][rl] = v4;
        }
      }
    __syncthreads();                            // S2
    if (tid < RPB) {
      uint32_t v1 = L1[0][tid], v2 = L2[0][tid], v3 = L3[0][tid], v4 = L4[0][tid];
      #pragma unroll
      for (int w = 1; w < 4; ++w) {
        ins4(v1, v2, v3, v4, L1[w][tid]);
        ins4(v1, v2, v3, v4, L2[w][tid]);
        ins4(v1, v2, v3, v4, L3[w][tid]);
        ins4(v1, v2, v3, v4, L4[w][tid]);
      }
      int a1 = (int)(v1 & 2047u), a2 = (int)(v2 & 2047u), a3 = (int)(v3 & 2047u);
      float f1 = unpacksc(v1), f2 = unpacksc(v2), f4 = unpacksc(v4);
      codes_s[tid] = a1;
      int rg = row0 + tid;
      codes_f[((size_t)(rg >> 12)*NBOOKS + ib)*TT + (rg & (TT-1))] = (float)a1;
      if (ib == 0) codes0[rg] = a1;
      if (f4 - f1 < EPS_FULL) {
        flist[atomicAdd(&nfull, 1)] = tid;
      } else if (f2 - f1 < EPS_PAIR) {
        int p = atomicAdd(&ncand, 1);
        cA[p] = tid | (a1 << 6) | (a2 << 17);
        cB[p] = a3;
      }
    }
    __syncthreads();                            // S3

    // ---- full fp64 re-rank (RARE: 4 codes within EPS of best) ----
    int nfl = nfull;
    for (int f = 0; f < nfl; ++f) {
      int row = flist[f];
      double bestv = DBL_MAX; int besti = 0x7fffffff;
      #pragma unroll
      for (int q = 0; q < 8; ++q) {
        int k = q*256 + tid;
        const float* er = Eb + (size_t)k*DD;
        double s0 = 0.0, s1 = 0.0;
        for (int d = 0; d < DD; d += 8) {
          float4 e0 = *(const float4*)(er + d);
          float4 e1 = *(const float4*)(er + d + 4);
          double x0 = (double)Z[row][d+0] - (double)e0.x;
          double x1 = (double)Z[row][d+1] - (double)e0.y;
          double x2 = (double)Z[row][d+2] - (double)e0.z;
          double x3 = (double)Z[row][d+3] - (double)e0.w;
          s0 += x0*x0 + x1*x1 + x2*x2 + x3*x3;
          double x4 = (double)Z[row][d+4] - (double)e1.x;
          double x5 = (double)Z[row][d+5] - (double)e1.y;
          double x6 = (double)Z[row][d+6] - (double)e1.z;
          double x7 = (double)Z[row][d+7] - (double)e1.w;
          s1 += x4*x4 + x5*x5 + x6*x6 + x7*x7;
        }
        double s = s0 + s1;
        if (s < bestv || (s == bestv && k < besti)) { bestv = s; besti = k; }
      }
      #pragma unroll
      for (int m = 1; m <= 32; m <<= 1) {
        double ov = __shfl_xor(bestv, m);
        int    oi = __shfl_xor(besti, m);
        if (ov < bestv || (ov == bestv && oi < besti)) { bestv = ov; besti = oi; }
      }
      if (lane == 0) { Rv[wave] = bestv; Ri[wave] = besti; }
      __syncthreads();
      if (tid == 0) {
        double bvv = Rv[0]; int bii = Ri[0];
        #pragma unroll
        for (int w = 1; w < 4; ++w)
          if (Rv[w] < bvv || (Rv[w] == bvv && Ri[w] < bii)) { bvv = Rv[w]; bii = Ri[w]; }
        codes_s[row] = bii;
        int rg = row0 + row;
        codes_f[((size_t)(rg >> 12)*NBOOKS + ib)*TT + (rg & (TT-1))] = (float)bii;
        if (ib == 0) codes0[rg] = bii;
      }
      __syncthreads();
    }

    // ---- candidate refine: exact fp64 over top-3 (one wave per row) ----
    {
      int ncd = ncand;
      for (int f = wave; f < ncd; f += 4) {
        int pk = cA[f];
        int row = pk & 63;
        int cand[3];
        cand[0] = (pk >> 6) & 2047;
        cand[1] = (pk >> 17) & 2047;
        cand[2] = cB[f];
        double bv = DBL_MAX; int bi = 0x7fffffff;
        #pragma unroll
        for (int t = 0; t < 3; ++t) {
          int cc = cand[t];
          const float* er = Eb + (size_t)cc*DD + lane*4;
          const float* zr = &Z[row][lane*4];
          double d0 = (double)zr[0] - (double)er[0];
          double d1 = (double)zr[1] - (double)er[1];
          double d2 = (double)zr[2] - (double)er[2];
          double d3 = (double)zr[3] - (double)er[3];
          double s = d0*d0 + d1*d1 + d2*d2 + d3*d3;
          #pragma unroll
          for (int m = 1; m <= 32; m <<= 1) s += __shfl_xor(s, m);
          if (s < bv || (s == bv && cc < bi)) { bv = s; bi = cc; }
        }
        if (lane == 0) {
          codes_s[row] = bi;
          int rg = row0 + row;
          codes_f[((size_t)(rg >> 12)*NBOOKS + ib)*TT + (rg & (TT-1))] = (float)bi;
          if (ib == 0) codes0[rg] = bi;
        }
      }
    }
    __syncthreads();                            // S4: codes_s final

    // ---- f32 residual subtract in LDS (acoustic books only) ----
    if (ib >= 1) {
      int code = codes_s[sr];
      const float* er = Eb + (size_t)code*DD;
      #pragma unroll
      for (int j = 0; j < 8; ++j) {
        int c = sg*4 + j*32;
        float4 e = *(const float4*)(er + c);
        float4 z = *(const float4*)&Z[sr][c];
        z.x -= e.x; z.y -= e.y; z.z -= e.z; z.w -= e.w;
        *(float4*)&Z[sr][c] = z;
      }
    }
    __syncthreads();                            // S5: Z stable for next book
  }

  // ---- aco = xa_initial - xa_final ----
  {
    const float* xp = xa_g + (size_t)(row0 + ldr)*DD + cg*32;
    float*       ap = aco_g + (size_t)(row0 + ldr)*DD + cg*32;
    #pragma unroll
    for (int j = 0; j < 8; ++j) {
      float4 x0 = *(const float4*)(xp + j*4);
      float4 zf = *(const float4*)&Z[ldr][cg*32 + j*4];
      float4 o;
      o.x = x0.x - zf.x; o.y = x0.y - zf.y; o.z = x0.z - zf.z; o.w = x0.w - zf.w;
      *(float4*)(ap + j*4) = o;
    }
  }
}

// ---------------- decode ----------------
__global__ __launch_bounds__(256) void final_kernel(
    const float* __restrict__ Wos, const float* __restrict__ Woa,
    const float* __restrict__ E0, const int* __restrict__ codes0,
    const float* __restrict__ aco, float* __restrict__ out)
{
  __shared__ float wsl[16*68], wal[16*68], sml[16*68], acl[16*68];
  const int tid = threadIdx.x;
  const int t0 = blockIdx.x*64, c0 = blockIdx.y*64, b = blockIdx.z;
  const int u = tid & 63, dq = tid >> 6;
  const int tx = tid & 15, ty = tid >> 4;
  int code = codes0[b*TT + t0 + u];
  const float* smr = E0 + (size_t)code*DD;
  const float* acr = aco + (size_t)(b*TT + t0 + u)*DD;
  const float* wsr = Wos + (size_t)(c0+u)*DD;
  const float* war = Woa + (size_t)(c0+u)*DD;
  float accS[4][4] = {{0}}, accA[4][4] = {{0}};
  for (int dc0 = 0; dc0 < DD; dc0 += 16) {
    __syncthreads();
    float4 v;
    v = *(const float4*)(wsr + dc0 + dq*4);
    wsl[(dq*4+0)*68+u]=v.x; wsl[(dq*4+1)*68+u]=v.y; wsl[(dq*4+2)*68+u]=v.z; wsl[(dq*4+3)*68+u]=v.w;
    v = *(const float4*)(war + dc0 + dq*4);
    wal[(dq*4+0)*68+u]=v.x; wal[(dq*4+1)*68+u]=v.y; wal[(dq*4+2)*68+u]=v.z; wal[(dq*4+3)*68+u]=v.w;
    v = *(const float4*)(smr + dc0 + dq*4);
    sml[(dq*4+0)*68+u]=v.x; sml[(dq*4+1)*68+u]=v.y; sml[(dq*4+2)*68+u]=v.z; sml[(dq*4+3)*68+u]=v.w;
    v = *(const float4*)(acr + dc0 + dq*4);
    acl[(dq*4+0)*68+u]=v.x; acl[(dq*4+1)*68+u]=v.y; acl[(dq*4+2)*68+u]=v.z; acl[(dq*4+3)*68+u]=v.w;
    __syncthreads();
    #pragma unroll
    for (int d = 0; d < 16; ++d) {
      float4 cs = *(const float4*)&wsl[d*68 + tx*4];
      float4 ca = *(const float4*)&wal[d*68 + tx*4];
      float4 ts = *(const float4*)&sml[d*68 + ty*4];
      float4 ta = *(const float4*)&acl[d*68 + ty*4];
      float csf[4]={cs.x,cs.y,cs.z,cs.w}, caf[4]={ca.x,ca.y,ca.z,ca.w};
      float tsf[4]={ts.x,ts.y,ts.z,ts.w}, taf[4]={ta.x,ta.y,ta.z,ta.w};
      #pragma unroll
      for (int i = 0; i < 4; ++i)
        #pragma unroll
        for (int j = 0; j < 4; ++j) {
          accS[i][j] = fmaf(csf[i], tsf[j], accS[i][j]);
          accA[i][j] = fmaf(caf[i], taf[j], accA[i][j]);
        }
    }
  }
  size_t ob = (size_t)b*CC*TT;
  #pragma unroll
  for (int i = 0; i < 4; ++i) {
    float4 r;
    r.x = accS[i][0] + accA[i][0];
    r.y = accS[i][1] + accA[i][1];
    r.z = accS[i][2] + accA[i][2];
    r.w = accS[i][3] + accA[i][3];
    *(float4*)&out[ob + (size_t)(c0 + tx*4 + i)*TT + t0 + ty*4] = r;
  }
}

extern "C" void kernel_launch(void* const* d_in, const int* in_sizes, int n_in,
                              void* d_out, int out_size, void* d_ws, size_t ws_size,
                              hipStream_t stream) {
  const float* x    = (const float*)d_in[0];
  const float* Wins = (const float*)d_in[1];
  const float* Wina = (const float*)d_in[2];
  const float* Wos  = (const float*)d_in[3];
  const float* Woa  = (const float*)d_in[4];
  const float* E    = (const float*)d_in[5];
  float* out = (float*)d_out;
  float* codes_f = out + (size_t)BB*CC*TT;

  // E16 plane lives in the front of d_out (18.9MB; codes_f starts at 33.6MB;
  // out[0:8.4M floats] fully overwritten by final_kernel afterwards).
  _Float16* E16 = (_Float16*)d_out;

  float* xs  = (float*)d_ws;
  float* xa  = xs + (size_t)MM*DD;
  float* aco = xa + (size_t)MM*DD;
  float* e2  = aco + (size_t)MM*DD;
  int* codes_i = (int*)(e2 + 18*KK);

  proj_kernel<<<dim3(TT/64, DD/64, BB), 256, 0, stream>>>(x, Wins, Wina, xs, xa);
  e2_kernel<<<(18*KK*64)/256, 256, 0, stream>>>(E, e2);
  cvt_e16_kernel<<<(18*KK*DD)/8/256, 256, 0, stream>>>(E, E16);

  fused_encode_kernel<<<MM/RPB, 256, 0, stream>>>(xs, xa, E, E16, e2,
                                                  codes_i, codes_f, aco);

  final_kernel<<<dim3(TT/64, CC/64, BB), 256, 0, stream>>>(Wos, Woa, E, codes_i, aco, out);
}